// Round 9
// baseline (625.561 us; speedup 1.0000x reference)
//
#include <hip/hip_runtime.h>

#define NGRAPH 256
#define NNODE  1000
#define NEDGE  16000
#define DIM    32
#define HSTR   20   // h row stride in floats (80B: 16B-aligned, spreads banks)

__device__ __forceinline__ unsigned monof(float f) {
  unsigned b = __float_as_uint(f);
  return (b & 0x80000000u) ? ~b : (b | 0x80000000u);
}

__device__ __forceinline__ float4 f4max(float4 a, float4 b) {
  return make_float4(fmaxf(a.x,b.x), fmaxf(a.y,b.y), fmaxf(a.z,b.z), fmaxf(a.w,b.w));
}
__device__ __forceinline__ float4 f4relu(float4 a) {
  return make_float4(fmaxf(a.x,0.f), fmaxf(a.y,0.f), fmaxf(a.z,0.f), fmaxf(a.w,0.f));
}
__device__ __forceinline__ float4 f4scale(float4 a, float s) {
  return make_float4(a.x*s, a.y*s, a.z*s, a.w*s);
}
__device__ __forceinline__ float4 f4add(float4 a, float4 b) {
  return make_float4(a.x+b.x, a.y+b.y, a.z+b.z, a.w+b.w);
}
__device__ __forceinline__ float dot4(float4 a, float4 b) {
  return a.x*b.x + a.y*b.y + a.z*b.z + a.w*b.w;
}
__device__ __forceinline__ float4 shfl4(float4 v, int m) {
  return make_float4(__shfl_xor(v.x,m,64), __shfl_xor(v.y,m,64),
                     __shfl_xor(v.z,m,64), __shfl_xor(v.w,m,64));
}

struct __align__(16) Smem {
  union { float h[NNODE * HSTR]; unsigned stage[NEDGE]; } hu;  // 80000 B
  unsigned short csr[NEDGE];      // 32000
  unsigned rowStart[1004];        // 4016
  unsigned cnt[1024];             // 4096
  float score[1024];              // 4096
  unsigned short perm[1024];      // 2048
  short nidx[1024];               // 2048
  short mp[1024];                 // 2048
  unsigned hist[260];             // 1040
  unsigned wsum[16];              // 64
  float redm[512];                // 2048
  float reds[512];                // 2048
  float eacc[64];                 // 256
  float hbuf[48];                 // 192  => 136000 B total
};

// exclusive block scan over 1024 threads; leaves total in wsum[15]
__device__ __forceinline__ unsigned blockExclScan(unsigned v, unsigned* wsum, int tid) {
  __syncthreads();
  int lane = tid & 63, w = tid >> 6;
  unsigned x = v;
  #pragma unroll
  for (int d = 1; d < 64; d <<= 1) {
    unsigned t = __shfl_up(x, d, 64);
    if (lane >= d) x += t;
  }
  if (lane == 63) wsum[w] = x;
  __syncthreads();
  if (w == 0) {
    unsigned s = (lane < 16) ? wsum[lane] : 0u;
    #pragma unroll
    for (int d = 1; d < 16; d <<= 1) {
      unsigned t = __shfl_up(s, d, 64);
      if (lane >= d) s += t;
    }
    if (lane < 16) wsum[lane] = s;
  }
  __syncthreads();
  unsigned base = (w > 0) ? wsum[w - 1] : 0u;
  return base + x - v;
}

// dot of 8 float4 weight words against x0..x7 (locals in scope)
#define XDOT(P4, R, S, O) ( dot4((P4)[(R)*(S)+(O)  ], x0) + dot4((P4)[(R)*(S)+(O)+1], x1) \
                          + dot4((P4)[(R)*(S)+(O)+2], x2) + dot4((P4)[(R)*(S)+(O)+3], x3) \
                          + dot4((P4)[(R)*(S)+(O)+4], x4) + dot4((P4)[(R)*(S)+(O)+5], x5) \
                          + dot4((P4)[(R)*(S)+(O)+6], x6) + dot4((P4)[(R)*(S)+(O)+7], x7) )
#define HV4(v, R)  v.x = fmaxf(Bv[(R)]+XDOT(W4,(R),8,0),0.f); v.y = fmaxf(Bv[(R)+1]+XDOT(W4,(R)+1,8,0),0.f); \
                   v.z = fmaxf(Bv[(R)+2]+XDOT(W4,(R)+2,8,0),0.f); v.w = fmaxf(Bv[(R)+3]+XDOT(W4,(R)+3,8,0),0.f);
// fold one float4 column-quarter (CQ in [0,16)) of U into the z accumulator
#define ZFOLD(zz, R, CQ, A) zz.x += dot4(U4[(R)*16+(CQ)], (A)); zz.y += dot4(U4[((R)+1)*16+(CQ)], (A)); \
                            zz.z += dot4(U4[((R)+2)*16+(CQ)], (A)); zz.w += dot4(U4[((R)+3)*16+(CQ)], (A));
#define ZFOLD_ALL(CQ, A) ZFOLD(z0,0,(CQ),(A)) ZFOLD(z1,4,(CQ),(A)) ZFOLD(z2,8,(CQ),(A)) ZFOLD(z3,12,(CQ),(A)) \
                         ZFOLD(z4,16,(CQ),(A)) ZFOLD(z5,20,(CQ),(A)) ZFOLD(z6,24,(CQ),(A)) ZFOLD(z7,28,(CQ),(A))
#define REDCH(v, OFF) do { \
  float4 mx = act ? (v) : make_float4(-__builtin_inff(),-__builtin_inff(),-__builtin_inff(),-__builtin_inff()); \
  float4 sv = act ? (v) : make_float4(0.f,0.f,0.f,0.f); \
  mx = f4max(mx, shfl4(mx,32)); sv = f4add(sv, shfl4(sv,32)); \
  mx = f4max(mx, shfl4(mx,16)); sv = f4add(sv, shfl4(sv,16)); \
  mx = f4max(mx, shfl4(mx, 8)); sv = f4add(sv, shfl4(sv, 8)); \
  mx = f4max(mx, shfl4(mx, 4)); sv = f4add(sv, shfl4(sv, 4)); \
  mx = f4max(mx, shfl4(mx, 2)); sv = f4add(sv, shfl4(sv, 2)); \
  mx = f4max(mx, shfl4(mx, 1)); sv = f4add(sv, shfl4(sv, 1)); \
  if (lane == 0) { *((float4*)(sm.redm + wv*32 + (OFF))) = mx; *((float4*)(sm.reds + wv*32 + (OFF))) = sv; } \
} while (0)

extern "C" __global__ void __launch_bounds__(1024, 1)
gnn_topk_kernel(const int* __restrict__ x_ids, const int* __restrict__ eidx,
                const float* __restrict__ emb,
                const float* __restrict__ w1, const float* __restrict__ b1,
                const float* __restrict__ u1, const float* __restrict__ p1,
                const float* __restrict__ w2, const float* __restrict__ b2,
                const float* __restrict__ u2, const float* __restrict__ p2,
                const float* __restrict__ w3, const float* __restrict__ b3,
                const float* __restrict__ u3, const float* __restrict__ p3,
                const float* __restrict__ l1w, const float* __restrict__ l1b,
                const float* __restrict__ l2w, const float* __restrict__ l2b,
                const float* __restrict__ l3w, const float* __restrict__ l3b,
                float* __restrict__ out)
{
  const int g = blockIdx.x;
  const int tid = (int)threadIdx.x;
  const int lane = tid & 63, wv = tid >> 6;

  __shared__ Smem sm;
  float* h_lds = sm.hu.h;

  const int* esrc = eidx + (size_t)g * (2 * NEDGE);
  const int* edst = esrc + NEDGE;

  // ---- init: x = emb[ids] ----
  float4 x0,x1,x2,x3,x4,x5,x6,x7;
  if (tid < NNODE) {
    int id = x_ids[(size_t)g * NNODE + tid];
    const float4* ep = (const float4*)(emb + id * DIM);
    x0=ep[0]; x1=ep[1]; x2=ep[2]; x3=ep[3]; x4=ep[4]; x5=ep[5]; x6=ep[6]; x7=ep[7];
  } else {
    x0=x1=x2=x3=x4=x5=x6=x7=make_float4(0.f,0.f,0.f,0.f);
  }
  sm.mp[tid] = (tid < NNODE) ? (short)tid : (short)-1;
  if (tid < 64) sm.eacc[tid] = 0.f;
  __syncthreads();

  int n = NNODE;
  #pragma unroll 1
  for (int layer = 0; layer < 3; ++layer) {
    const float* W  = (layer==0)? w1 : (layer==1)? w2 : w3;
    const float* Bv = (layer==0)? b1 : (layer==1)? b2 : b3;
    const float* U  = (layer==0)? u1 : (layer==1)? u2 : u3;
    const float* P  = (layer==0)? p1 : (layer==1)? p2 : p3;
    const int k     = (layer==0)? 800 : (layer==1)? 640 : 512;
    const float4* W4 = (const float4*)W;
    const float4* U4 = (const float4*)U;

    // ---- CSR build: single global edge pass, stage mapped pairs in LDS ----
    sm.cnt[tid] = 0u;
    __syncthreads();
    for (int e = tid; e < NEDGE; e += 1024) {
      int s = sm.mp[esrc[e]];
      int d = sm.mp[edst[e]];
      unsigned pk = 0xFFFFFFFFu;
      if (s >= 0 && d >= 0) {
        pk = ((unsigned)d << 16) | (unsigned)s;
        atomicAdd(&sm.cnt[d], 1u);
      }
      sm.hu.stage[e] = pk;
    }
    __syncthreads();
    unsigned cv = sm.cnt[tid];
    unsigned excl = blockExclScan(cv, sm.wsum, tid);
    unsigned total = sm.wsum[15];
    if (tid < n) sm.rowStart[tid] = excl;
    if (tid == 0) sm.rowStart[n] = total;
    sm.cnt[tid] = excl;              // cursor
    __syncthreads();
    for (int e = tid; e < NEDGE; e += 1024) {
      unsigned pk = sm.hu.stage[e];
      if (pk != 0xFFFFFFFFu) {
        unsigned d = pk >> 16;
        unsigned pos = atomicAdd(&sm.cnt[d], 1u);
        sm.csr[pos] = (unsigned short)(pk & 0xFFFFu);
      }
    }
    __syncthreads();   // stage consumed; csr complete; h region reusable

    float4* hp = (float4*)(h_lds + tid * HSTR);

    // ---- P1: h0 = relu(W[0:16]@x+b) -> own row (live: x) ----
    if (tid < n) {
      float4 t;
      HV4(t,0)  hp[0]=t;
      HV4(t,4)  hp[1]=t;
      HV4(t,8)  hp[2]=t;
      HV4(t,12) hp[3]=t;
    }
    __syncthreads();   // h0 visible

    // ---- P2: walk h0 (live: x + A), then fold U[:,0:16]@A -> z born ----
    float4 z0,z1,z2,z3,z4,z5,z6,z7;
    z0=z1=z2=z3=z4=z5=z6=z7=make_float4(0.f,0.f,0.f,0.f);
    if (tid < n) {
      const unsigned beg = sm.rowStart[tid], end = sm.rowStart[tid+1];
      float4 A0 = hp[0], A1 = hp[1], A2 = hp[2], A3 = hp[3];
      #pragma unroll 1
      for (unsigned e = beg; e < end; ++e) {
        const float4* rp = (const float4*)(h_lds + sm.csr[e]*HSTR);
        A0 = f4max(A0, rp[0]); A1 = f4max(A1, rp[1]);
        A2 = f4max(A2, rp[2]); A3 = f4max(A3, rp[3]);
      }
      ZFOLD_ALL(0, A0) ZFOLD_ALL(1, A1) ZFOLD_ALL(2, A2) ZFOLD_ALL(3, A3)
    }
    __syncthreads();   // all h0 reads done; rows reusable

    // ---- P3: h1 = relu(W[16:32]@x+b) -> rows; fold U[:,32:64]@x (x dies) ----
    if (tid < n) {
      float4 t;
      HV4(t,16) hp[0]=t;
      HV4(t,20) hp[1]=t;
      HV4(t,24) hp[2]=t;
      HV4(t,28) hp[3]=t;
      ZFOLD_ALL( 8,x0) ZFOLD_ALL( 9,x1) ZFOLD_ALL(10,x2) ZFOLD_ALL(11,x3)
      ZFOLD_ALL(12,x4) ZFOLD_ALL(13,x5) ZFOLD_ALL(14,x6) ZFOLD_ALL(15,x7)
    }
    __syncthreads();   // h1 visible

    // ---- P4: walk h1 (live: z + A), fold U[:,16:32]@A; x = relu(z) ----
    if (tid < n) {
      const unsigned beg = sm.rowStart[tid], end = sm.rowStart[tid+1];
      float4 A0 = hp[0], A1 = hp[1], A2 = hp[2], A3 = hp[3];
      #pragma unroll 1
      for (unsigned e = beg; e < end; ++e) {
        const float4* rp = (const float4*)(h_lds + sm.csr[e]*HSTR);
        A0 = f4max(A0, rp[0]); A1 = f4max(A1, rp[1]);
        A2 = f4max(A2, rp[2]); A3 = f4max(A3, rp[3]);
      }
      ZFOLD_ALL(4, A0) ZFOLD_ALL(5, A1) ZFOLD_ALL(6, A2) ZFOLD_ALL(7, A3)
      x0=f4relu(z0); x1=f4relu(z1); x2=f4relu(z2); x3=f4relu(z3);
      x4=f4relu(z4); x5=f4relu(z5); x6=f4relu(z6); x7=f4relu(z7);
    }

    // ---- pool: score = tanh(x.p/||p||) ----
    float pn = 0.f;
    for (int c = 0; c < DIM; ++c) pn += P[c] * P[c];
    pn = sqrtf(pn);
    const float4* P4 = (const float4*)P;
    unsigned key = 0xFFFFFFFFu;
    if (tid < n) {
      float dp = dot4(P4[0],x0)+dot4(P4[1],x1)+dot4(P4[2],x2)+dot4(P4[3],x3)
               + dot4(P4[4],x4)+dot4(P4[5],x5)+dot4(P4[6],x6)+dot4(P4[7],x7);
      float sc = tanhf(dp / pn);
      sm.score[tid] = sc;
      key = ~monof(sc);
    }
    __syncthreads();   // P4 row reads done -> rows free
    // stash x half0 in rows so only x4..x7 stay live through the select
    if (tid < n) { hp[0]=x0; hp[1]=x1; hp[2]=x2; hp[3]=x3; }

    // ---- exact top-k via 4-pass radix select ----
    bool cand = (tid < n);
    bool sel = false;
    unsigned target = (unsigned)k;
    #pragma unroll 1
    for (int pass = 0; pass < 4; ++pass) {
      for (int i = tid; i < 257; i += 1024) sm.hist[i] = 0u;
      __syncthreads();
      unsigned dig = (key >> (24 - 8*pass)) & 255u;
      if (cand) atomicAdd(&sm.hist[dig], 1u);
      __syncthreads();
      if (tid < 64) {
        unsigned q0 = sm.hist[tid*4], q1 = sm.hist[tid*4+1], q2 = sm.hist[tid*4+2], q3 = sm.hist[tid*4+3];
        unsigned s1 = q0+q1, s2v = s1+q2, s3 = s2v+q3;
        unsigned tot = s3;
        #pragma unroll
        for (int d = 1; d < 64; d <<= 1) {
          unsigned t = __shfl_up(tot, d, 64);
          if (lane >= d) tot += t;
        }
        unsigned base = tot - s3;
        sm.hist[tid*4] = base; sm.hist[tid*4+1] = base+q0; sm.hist[tid*4+2] = base+s1; sm.hist[tid*4+3] = base+s2v;
        if (tid == 63) sm.hist[256] = tot;
      }
      __syncthreads();
      if (cand) {
        unsigned lo = sm.hist[dig], hi = sm.hist[dig+1];
        if (hi <= target)      { sel = true;  cand = false; }
        else if (lo >= target) { cand = false; }
        else                   { target -= lo; }
      }
      __syncthreads();
    }
    unsigned trank = blockExclScan(cand ? 1u : 0u, sm.wsum, tid);
    if (cand && trank < target) sel = true;
    unsigned pos = blockExclScan(sel ? 1u : 0u, sm.wsum, tid);
    sm.nidx[tid] = -1;
    __syncthreads();
    if (sel) { sm.nidx[tid] = (short)pos; sm.perm[pos] = (unsigned short)tid; }
    __syncthreads();

    // ---- gather xn = x[perm]*vals (half0 already in rows) ----
    float4 n0,n1,n2,n3; float val = 0.f; int pj = 0;
    if (tid < k) {
      pj = sm.perm[tid];
      val = sm.score[pj];
      const float4* rp = (const float4*)(h_lds + pj * HSTR);
      n0 = f4scale(rp[0], val); n1 = f4scale(rp[1], val);
      n2 = f4scale(rp[2], val); n3 = f4scale(rp[3], val);
    }
    __syncthreads();
    if (tid < n) { hp[0]=x4; hp[1]=x5; hp[2]=x6; hp[3]=x7; }
    __syncthreads();
    if (tid < k) {
      const float4* rp = (const float4*)(h_lds + pj * HSTR);
      x4 = f4scale(rp[0], val); x5 = f4scale(rp[1], val);
      x6 = f4scale(rp[2], val); x7 = f4scale(rp[3], val);
      x0 = n0; x1 = n1; x2 = n2; x3 = n3;
    } else {
      x0=x1=x2=x3=x4=x5=x6=x7=make_float4(0.f,0.f,0.f,0.f);
    }
    // compose orig->current map
    {
      short m0 = sm.mp[tid];
      if (m0 >= 0) sm.mp[tid] = sm.nidx[m0];
    }
    n = k;

    // ---- readout: gmp || gap on pooled x, accumulate into eacc ----
    {
      bool act = (tid < n);
      REDCH(x0, 0); REDCH(x1, 4); REDCH(x2, 8);  REDCH(x3, 12);
      REDCH(x4,16); REDCH(x5,20); REDCH(x6,24);  REDCH(x7,28);
    }
    __syncthreads();
    if (tid < 32) {
      float rm = -__builtin_inff(), rs = 0.f;
      #pragma unroll
      for (int w_ = 0; w_ < 16; ++w_) {
        rm = fmaxf(rm, sm.redm[w_*32 + tid]);
        rs += sm.reds[w_*32 + tid];
      }
      sm.eacc[tid] += rm;
      sm.eacc[32 + tid] += rs / (float)n;
    }
    __syncthreads();
  }

  // ---- MLP head ----
  if (tid < 32) {
    float v = l1b[tid];
    #pragma unroll
    for (int c = 0; c < 64; ++c) v += l1w[tid*64 + c] * sm.eacc[c];
    sm.hbuf[tid] = fmaxf(v, 0.f);
  }
  __syncthreads();
  if (tid < 16) {
    float v = l2b[tid];
    #pragma unroll
    for (int c = 0; c < 32; ++c) v += l2w[tid*32 + c] * sm.hbuf[c];
    sm.hbuf[32 + tid] = fmaxf(v, 0.f);
  }
  __syncthreads();
  if (tid == 0) {
    float v = l3b[0];
    #pragma unroll
    for (int c = 0; c < 16; ++c) v += l3w[c] * sm.hbuf[32 + c];
    out[g] = 1.f / (1.f + expf(-v));
  }
  if (tid < 64) out[NGRAPH + (size_t)g*64 + tid] = sm.eacc[tid];
}

extern "C" void kernel_launch(void* const* d_in, const int* in_sizes, int n_in,
                              void* d_out, int out_size, void* d_ws, size_t ws_size,
                              hipStream_t stream) {
  (void)in_sizes; (void)n_in; (void)d_ws; (void)ws_size; (void)out_size;
  const int*   x_ids = (const int*)d_in[0];
  const int*   eidx  = (const int*)d_in[1];
  const float* emb   = (const float*)d_in[2];
  const float* w1 = (const float*)d_in[3],  *b1 = (const float*)d_in[4];
  const float* u1 = (const float*)d_in[5],  *p1 = (const float*)d_in[6];
  const float* w2 = (const float*)d_in[7],  *b2 = (const float*)d_in[8];
  const float* u2 = (const float*)d_in[9],  *p2 = (const float*)d_in[10];
  const float* w3 = (const float*)d_in[11], *b3 = (const float*)d_in[12];
  const float* u3 = (const float*)d_in[13], *p3 = (const float*)d_in[14];
  const float* l1w = (const float*)d_in[15], *l1b = (const float*)d_in[16];
  const float* l2w = (const float*)d_in[17], *l2b = (const float*)d_in[18];
  const float* l3w = (const float*)d_in[19], *l3b = (const float*)d_in[20];
  float* out = (float*)d_out;

  gnn_topk_kernel<<<dim3(NGRAPH), dim3(1024), 0, stream>>>(
      x_ids, eidx, emb,
      w1, b1, u1, p1, w2, b2, u2, p2, w3, b3, u3, p3,
      l1w, l1b, l2w, l2b, l3w, l3b, out);
}

// Round 10
// 366.658 us; speedup vs baseline: 1.7061x; 1.7061x over previous
//
#include <hip/hip_runtime.h>

#define NGRAPH 256
#define NNODE  1000
#define NEDGE  16000
#define DIM    32
#define HSTR   20   // h row stride in floats (80B: 16B-aligned, spreads banks)

__device__ __forceinline__ unsigned monof(float f) {
  unsigned b = __float_as_uint(f);
  return (b & 0x80000000u) ? ~b : (b | 0x80000000u);
}

__device__ __forceinline__ float4 f4max(float4 a, float4 b) {
  return make_float4(fmaxf(a.x,b.x), fmaxf(a.y,b.y), fmaxf(a.z,b.z), fmaxf(a.w,b.w));
}
__device__ __forceinline__ float4 f4relu(float4 a) {
  return make_float4(fmaxf(a.x,0.f), fmaxf(a.y,0.f), fmaxf(a.z,0.f), fmaxf(a.w,0.f));
}
__device__ __forceinline__ float4 f4scale(float4 a, float s) {
  return make_float4(a.x*s, a.y*s, a.z*s, a.w*s);
}
__device__ __forceinline__ float4 f4add(float4 a, float4 b) {
  return make_float4(a.x+b.x, a.y+b.y, a.z+b.z, a.w+b.w);
}
__device__ __forceinline__ float dot4(float4 a, float4 b) {
  return a.x*b.x + a.y*b.y + a.z*b.z + a.w*b.w;
}
__device__ __forceinline__ float4 shfl4(float4 v, int m) {
  return make_float4(__shfl_xor(v.x,m,64), __shfl_xor(v.y,m,64),
                     __shfl_xor(v.z,m,64), __shfl_xor(v.w,m,64));
}
__device__ __forceinline__ float4 lds4(const float* p) { return *(const float4*)p; }

struct __align__(16) Smem {
  union { float h[NNODE * HSTR]; unsigned stage[NEDGE]; } hu;  // 80000 B
  unsigned short csr[NEDGE];      // 32000
  unsigned rowStart[1004];        // 4016
  unsigned cnt[1024];             // 4096
  float score[1024];              // 4096
  unsigned short perm[1024];      // 2048
  short nidx[1024];               // 2048
  short mp[1024];                 // 2048
  unsigned hist[260];             // 1040
  unsigned wsum[16];              // 64
  float redm[512];                // 2048
  float reds[512];                // 2048
  float eacc[64];                 // 256
  float hbuf[48];                 // 192  => 136000 B total
};

// exclusive block scan over 1024 threads; leaves total in wsum[15]
__device__ __forceinline__ unsigned blockExclScan(unsigned v, unsigned* wsum, int tid) {
  __syncthreads();
  int lane = tid & 63, w = tid >> 6;
  unsigned x = v;
  #pragma unroll
  for (int d = 1; d < 64; d <<= 1) {
    unsigned t = __shfl_up(x, d, 64);
    if (lane >= d) x += t;
  }
  if (lane == 63) wsum[w] = x;
  __syncthreads();
  if (w == 0) {
    unsigned s = (lane < 16) ? wsum[lane] : 0u;
    #pragma unroll
    for (int d = 1; d < 16; d <<= 1) {
      unsigned t = __shfl_up(s, d, 64);
      if (lane >= d) s += t;
    }
    if (lane < 16) wsum[lane] = s;
  }
  __syncthreads();
  unsigned base = (w > 0) ? wsum[w - 1] : 0u;
  return base + x - v;
}

// ---- AGPR stash primitives: compiler-tracked "a" register class ----
#define AST(nm, e)  asm volatile("v_accvgpr_write_b32 %0, %1" : "=a"(nm) : "v"(e))
#define ALD(d, nm)  asm volatile("v_accvgpr_read_b32 %0, %1" : "=v"(d) : "a"(nm))
#define DECLQ(nm)   float nm##0, nm##1, nm##2, nm##3
#define AST4(nm, v) AST(nm##0,(v).x); AST(nm##1,(v).y); AST(nm##2,(v).z); AST(nm##3,(v).w)
#define ALD4(v, nm) ALD((v).x,nm##0); ALD((v).y,nm##1); ALD((v).z,nm##2); ALD((v).w,nm##3)

// dot of 8 float4 weight words against x0..x7 (locals in scope)
#define XDOT(P4, R, S, O) ( dot4((P4)[(R)*(S)+(O)  ], x0) + dot4((P4)[(R)*(S)+(O)+1], x1) \
                          + dot4((P4)[(R)*(S)+(O)+2], x2) + dot4((P4)[(R)*(S)+(O)+3], x3) \
                          + dot4((P4)[(R)*(S)+(O)+4], x4) + dot4((P4)[(R)*(S)+(O)+5], x5) \
                          + dot4((P4)[(R)*(S)+(O)+6], x6) + dot4((P4)[(R)*(S)+(O)+7], x7) )
// dot of 4 float4 U words against h0..h3 (aggregated half)
#define GDOT(R, O) ( dot4(U4[(R)*16+(O)  ], h0) + dot4(U4[(R)*16+(O)+1], h1) \
                   + dot4(U4[(R)*16+(O)+2], h2) + dot4(U4[(R)*16+(O)+3], h3) )
#define HV4(v, R)  v.x = fmaxf(Bv[(R)]+XDOT(W4,(R),8,0),0.f); v.y = fmaxf(Bv[(R)+1]+XDOT(W4,(R)+1,8,0),0.f); \
                   v.z = fmaxf(Bv[(R)+2]+XDOT(W4,(R)+2,8,0),0.f); v.w = fmaxf(Bv[(R)+3]+XDOT(W4,(R)+3,8,0),0.f);
// a-quad ops living in AGPRs
#define AQ_INIT(nm, R) { float4 q_; q_.x=XDOT(U4,(R),16,8); q_.y=XDOT(U4,(R)+1,16,8); \
                         q_.z=XDOT(U4,(R)+2,16,8); q_.w=XDOT(U4,(R)+3,16,8); AST4(nm,q_); }
#define AQ_FOLD(nm, R) { float4 t_; ALD4(t_,nm); t_.x+=GDOT((R),0); t_.y+=GDOT((R)+1,0); \
                         t_.z+=GDOT((R)+2,0); t_.w+=GDOT((R)+3,0); AST4(nm,t_); }
#define AQ_FIN(xv, nm, R) { float4 t_; ALD4(t_,nm); t_.x+=GDOT((R),4); t_.y+=GDOT((R)+1,4); \
                            t_.z+=GDOT((R)+2,4); t_.w+=GDOT((R)+3,4); xv=f4relu(t_); }
#define REDCH(v, OFF) do { \
  float4 mx = act ? (v) : make_float4(-__builtin_inff(),-__builtin_inff(),-__builtin_inff(),-__builtin_inff()); \
  float4 sv = act ? (v) : make_float4(0.f,0.f,0.f,0.f); \
  mx = f4max(mx, shfl4(mx,32)); sv = f4add(sv, shfl4(sv,32)); \
  mx = f4max(mx, shfl4(mx,16)); sv = f4add(sv, shfl4(sv,16)); \
  mx = f4max(mx, shfl4(mx, 8)); sv = f4add(sv, shfl4(sv, 8)); \
  mx = f4max(mx, shfl4(mx, 4)); sv = f4add(sv, shfl4(sv, 4)); \
  mx = f4max(mx, shfl4(mx, 2)); sv = f4add(sv, shfl4(sv, 2)); \
  mx = f4max(mx, shfl4(mx, 1)); sv = f4add(sv, shfl4(sv, 1)); \
  if (lane == 0) { *((float4*)(sm.redm + wv*32 + (OFF))) = mx; *((float4*)(sm.reds + wv*32 + (OFF))) = sv; } \
} while (0)

extern "C" __global__ void
__attribute__((amdgpu_flat_work_group_size(1024,1024)))
__attribute__((amdgpu_waves_per_eu(4,4)))
gnn_topk_kernel(const int* __restrict__ x_ids, const int* __restrict__ eidx,
                const float* __restrict__ emb,
                const float* __restrict__ w1, const float* __restrict__ b1,
                const float* __restrict__ u1, const float* __restrict__ p1,
                const float* __restrict__ w2, const float* __restrict__ b2,
                const float* __restrict__ u2, const float* __restrict__ p2,
                const float* __restrict__ w3, const float* __restrict__ b3,
                const float* __restrict__ u3, const float* __restrict__ p3,
                const float* __restrict__ l1w, const float* __restrict__ l1b,
                const float* __restrict__ l2w, const float* __restrict__ l2b,
                const float* __restrict__ l3w, const float* __restrict__ l3b,
                float* __restrict__ out)
{
  const int g = blockIdx.x;
  const int tid = (int)threadIdx.x;
  const int lane = tid & 63, wv = tid >> 6;

  __shared__ Smem sm;
  float* h_lds = sm.hu.h;

  const int* esrc = eidx + (size_t)g * (2 * NEDGE);
  const int* edst = esrc + NEDGE;

  // ---- init: x = emb[ids] ----
  float4 x0,x1,x2,x3,x4,x5,x6,x7;
  if (tid < NNODE) {
    int id = x_ids[(size_t)g * NNODE + tid];
    const float4* ep = (const float4*)(emb + id * DIM);
    x0=ep[0]; x1=ep[1]; x2=ep[2]; x3=ep[3]; x4=ep[4]; x5=ep[5]; x6=ep[6]; x7=ep[7];
  } else {
    x0=x1=x2=x3=x4=x5=x6=x7=make_float4(0.f,0.f,0.f,0.f);
  }
  sm.mp[tid] = (tid < NNODE) ? (short)tid : (short)-1;
  if (tid < 64) sm.eacc[tid] = 0.f;
  __syncthreads();

  int n = NNODE;
  #pragma unroll 1
  for (int layer = 0; layer < 3; ++layer) {
    const float* W  = (layer==0)? w1 : (layer==1)? w2 : w3;
    const float* Bv = (layer==0)? b1 : (layer==1)? b2 : b3;
    const float* U  = (layer==0)? u1 : (layer==1)? u2 : u3;
    const float* P  = (layer==0)? p1 : (layer==1)? p2 : p3;
    const int k     = (layer==0)? 800 : (layer==1)? 640 : 512;
    const float4* W4 = (const float4*)W;
    const float4* U4 = (const float4*)U;

    // ---- CSR build: single global edge pass, stage mapped pairs in LDS ----
    sm.cnt[tid] = 0u;
    __syncthreads();
    for (int e = tid; e < NEDGE; e += 1024) {
      int s = sm.mp[esrc[e]];
      int d = sm.mp[edst[e]];
      unsigned pk = 0xFFFFFFFFu;
      if (s >= 0 && d >= 0) {
        pk = ((unsigned)d << 16) | (unsigned)s;
        atomicAdd(&sm.cnt[d], 1u);
      }
      sm.hu.stage[e] = pk;
    }
    __syncthreads();
    unsigned cv = sm.cnt[tid];
    unsigned excl = blockExclScan(cv, sm.wsum, tid);
    unsigned total = sm.wsum[15];
    if (tid < n) sm.rowStart[tid] = excl;
    if (tid == 0) sm.rowStart[n] = total;
    sm.cnt[tid] = excl;              // cursor
    __syncthreads();
    for (int e = tid; e < NEDGE; e += 1024) {
      unsigned pk = sm.hu.stage[e];
      if (pk != 0xFFFFFFFFu) {
        unsigned d = pk >> 16;
        unsigned pos = atomicAdd(&sm.cnt[d], 1u);
        sm.csr[pos] = (unsigned short)(pk & 0xFFFFu);
      }
    }
    __syncthreads();   // stage consumed; csr complete; h region reusable

    float4* hp = (float4*)(h_lds + tid * HSTR);

    // AGPR-resident state: aq* = accumulator (32 f), xq* = x stash (32 f)
    DECLQ(aq0); DECLQ(aq1); DECLQ(aq2); DECLQ(aq3);
    DECLQ(aq4); DECLQ(aq5); DECLQ(aq6); DECLQ(aq7);
    DECLQ(xq0); DECLQ(xq1); DECLQ(xq2); DECLQ(xq3);
    DECLQ(xq4); DECLQ(xq5); DECLQ(xq6); DECLQ(xq7);

    float4 h0,h1,h2,h3;
    // ---- A+B+C: h0 -> rows; a = U2@x -> AGPR; x -> AGPR ----
    if (tid < n) {
      HV4(h0,0) HV4(h1,4) HV4(h2,8) HV4(h3,12)
      hp[0]=h0; hp[1]=h1; hp[2]=h2; hp[3]=h3;
      AQ_INIT(aq0,0)  AQ_INIT(aq1,4)  AQ_INIT(aq2,8)  AQ_INIT(aq3,12)
      AQ_INIT(aq4,16) AQ_INIT(aq5,20) AQ_INIT(aq6,24) AQ_INIT(aq7,28)
      AST4(xq0,x0); AST4(xq1,x1); AST4(xq2,x2); AST4(xq3,x3);
      AST4(xq4,x4); AST4(xq5,x5); AST4(xq6,x6); AST4(xq7,x7);
    }
    __syncthreads();   // h0 visible

    // ---- D+E: walk h0 in place (h only live), fold U[:,0:16]@aggr0 into AGPR ----
    if (tid < n) {
      const unsigned beg = sm.rowStart[tid], end = sm.rowStart[tid+1];
      for (unsigned e = beg; e < end; ++e) {
        const float* rp = h_lds + sm.csr[e]*HSTR;
        h0 = f4max(h0, lds4(rp));   h1 = f4max(h1, lds4(rp+4));
        h2 = f4max(h2, lds4(rp+8)); h3 = f4max(h3, lds4(rp+12));
      }
      AQ_FOLD(aq0,0)  AQ_FOLD(aq1,4)  AQ_FOLD(aq2,8)  AQ_FOLD(aq3,12)
      AQ_FOLD(aq4,16) AQ_FOLD(aq5,20) AQ_FOLD(aq6,24) AQ_FOLD(aq7,28)
    }
    __syncthreads();   // all h0 reads done; rows reusable

    // ---- F+G: unstash x, h1 -> rows (x dies here) ----
    if (tid < n) {
      ALD4(x0,xq0); ALD4(x1,xq1); ALD4(x2,xq2); ALD4(x3,xq3);
      ALD4(x4,xq4); ALD4(x5,xq5); ALD4(x6,xq6); ALD4(x7,xq7);
      HV4(h0,16) HV4(h1,20) HV4(h2,24) HV4(h3,28)
      hp[0]=h0; hp[1]=h1; hp[2]=h2; hp[3]=h3;
    }
    __syncthreads();   // h1 visible

    // ---- H+I: walk h1 in place, final fold + relu -> new x ----
    if (tid < n) {
      const unsigned beg = sm.rowStart[tid], end = sm.rowStart[tid+1];
      for (unsigned e = beg; e < end; ++e) {
        const float* rp = h_lds + sm.csr[e]*HSTR;
        h0 = f4max(h0, lds4(rp));   h1 = f4max(h1, lds4(rp+4));
        h2 = f4max(h2, lds4(rp+8)); h3 = f4max(h3, lds4(rp+12));
      }
      AQ_FIN(x0,aq0,0)  AQ_FIN(x1,aq1,4)  AQ_FIN(x2,aq2,8)  AQ_FIN(x3,aq3,12)
      AQ_FIN(x4,aq4,16) AQ_FIN(x5,aq5,20) AQ_FIN(x6,aq6,24) AQ_FIN(x7,aq7,28)
    }

    // ---- pool: score = tanh(x.p/||p||) ----
    float pn = 0.f;
    for (int c = 0; c < DIM; ++c) pn += P[c] * P[c];
    pn = sqrtf(pn);
    const float4* P4 = (const float4*)P;
    unsigned key = 0xFFFFFFFFu;
    if (tid < n) {
      float dp = dot4(P4[0],x0)+dot4(P4[1],x1)+dot4(P4[2],x2)+dot4(P4[3],x3)
               + dot4(P4[4],x4)+dot4(P4[5],x5)+dot4(P4[6],x6)+dot4(P4[7],x7);
      float sc = tanhf(dp / pn);
      sm.score[tid] = sc;
      key = ~monof(sc);
    }
    bool cand = (tid < n);
    bool sel = false;
    unsigned target = (unsigned)k;
    #pragma unroll 1
    for (int pass = 0; pass < 4; ++pass) {
      for (int i = tid; i < 257; i += 1024) sm.hist[i] = 0u;
      __syncthreads();
      unsigned dig = (key >> (24 - 8*pass)) & 255u;
      if (cand) atomicAdd(&sm.hist[dig], 1u);
      __syncthreads();
      if (tid < 64) {
        unsigned q0 = sm.hist[tid*4], q1 = sm.hist[tid*4+1], q2 = sm.hist[tid*4+2], q3 = sm.hist[tid*4+3];
        unsigned s1 = q0+q1, s2v = s1+q2, s3 = s2v+q3;
        unsigned tot = s3;
        #pragma unroll
        for (int d = 1; d < 64; d <<= 1) {
          unsigned t = __shfl_up(tot, d, 64);
          if (lane >= d) tot += t;
        }
        unsigned base = tot - s3;
        sm.hist[tid*4] = base; sm.hist[tid*4+1] = base+q0; sm.hist[tid*4+2] = base+s1; sm.hist[tid*4+3] = base+s2v;
        if (tid == 63) sm.hist[256] = tot;
      }
      __syncthreads();
      if (cand) {
        unsigned lo = sm.hist[dig], hi = sm.hist[dig+1];
        if (hi <= target)      { sel = true;  cand = false; }
        else if (lo >= target) { cand = false; }
        else                   { target -= lo; }
      }
      __syncthreads();
    }
    unsigned trank = blockExclScan(cand ? 1u : 0u, sm.wsum, tid);
    if (cand && trank < target) sel = true;
    unsigned pos = blockExclScan(sel ? 1u : 0u, sm.wsum, tid);
    sm.nidx[tid] = -1;
    __syncthreads();
    if (sel) { sm.nidx[tid] = (short)pos; sm.perm[pos] = (unsigned short)tid; }
    __syncthreads();

    // ---- gather xn = x[perm]*vals through LDS (2 halves) ----
    if (tid < n) { hp[0]=x0; hp[1]=x1; hp[2]=x2; hp[3]=x3; }
    __syncthreads();
    float4 n0,n1,n2,n3; float val = 0.f; int pj = 0;
    if (tid < k) {
      pj = sm.perm[tid];
      val = sm.score[pj];
      const float* rp = h_lds + pj * HSTR;
      n0 = f4scale(lds4(rp),   val); n1 = f4scale(lds4(rp+4),  val);
      n2 = f4scale(lds4(rp+8), val); n3 = f4scale(lds4(rp+12), val);
    }
    __syncthreads();
    if (tid < n) { hp[0]=x4; hp[1]=x5; hp[2]=x6; hp[3]=x7; }
    __syncthreads();
    if (tid < k) {
      const float* rp = h_lds + pj * HSTR;
      x4 = f4scale(lds4(rp),   val); x5 = f4scale(lds4(rp+4),  val);
      x6 = f4scale(lds4(rp+8), val); x7 = f4scale(lds4(rp+12), val);
      x0 = n0; x1 = n1; x2 = n2; x3 = n3;
    } else {
      x0=x1=x2=x3=x4=x5=x6=x7=make_float4(0.f,0.f,0.f,0.f);
    }
    // compose orig->current map
    {
      short m0 = sm.mp[tid];
      if (m0 >= 0) sm.mp[tid] = sm.nidx[m0];
    }
    n = k;

    // ---- readout: gmp || gap on pooled x, accumulate into eacc ----
    {
      bool act = (tid < n);
      REDCH(x0, 0); REDCH(x1, 4); REDCH(x2, 8);  REDCH(x3, 12);
      REDCH(x4,16); REDCH(x5,20); REDCH(x6,24);  REDCH(x7,28);
    }
    __syncthreads();
    if (tid < 32) {
      float rm = -__builtin_inff(), rs = 0.f;
      #pragma unroll
      for (int w_ = 0; w_ < 16; ++w_) {
        rm = fmaxf(rm, sm.redm[w_*32 + tid]);
        rs += sm.reds[w_*32 + tid];
      }
      sm.eacc[tid] += rm;
      sm.eacc[32 + tid] += rs / (float)n;
    }
    __syncthreads();
  }

  // ---- MLP head ----
  if (tid < 32) {
    float v = l1b[tid];
    #pragma unroll
    for (int c = 0; c < 64; ++c) v += l1w[tid*64 + c] * sm.eacc[c];
    sm.hbuf[tid] = fmaxf(v, 0.f);
  }
  __syncthreads();
  if (tid < 16) {
    float v = l2b[tid];
    #pragma unroll
    for (int c = 0; c < 32; ++c) v += l2w[tid*32 + c] * sm.hbuf[c];
    sm.hbuf[32 + tid] = fmaxf(v, 0.f);
  }
  __syncthreads();
  if (tid == 0) {
    float v = l3b[0];
    #pragma unroll
    for (int c = 0; c < 16; ++c) v += l3w[c] * sm.hbuf[32 + c];
    out[g] = 1.f / (1.f + expf(-v));
  }
  if (tid < 64) out[NGRAPH + (size_t)g*64 + tid] = sm.eacc[tid];
}

extern "C" void kernel_launch(void* const* d_in, const int* in_sizes, int n_in,
                              void* d_out, int out_size, void* d_ws, size_t ws_size,
                              hipStream_t stream) {
  (void)in_sizes; (void)n_in; (void)d_ws; (void)ws_size; (void)out_size;
  const int*   x_ids = (const int*)d_in[0];
  const int*   eidx  = (const int*)d_in[1];
  const float* emb   = (const float*)d_in[2];
  const float* w1 = (const float*)d_in[3],  *b1 = (const float*)d_in[4];
  const float* u1 = (const float*)d_in[5],  *p1 = (const float*)d_in[6];
  const float* w2 = (const float*)d_in[7],  *b2 = (const float*)d_in[8];
  const float* u2 = (const float*)d_in[9],  *p2 = (const float*)d_in[10];
  const float* w3 = (const float*)d_in[11], *b3 = (const float*)d_in[12];
  const float* u3 = (const float*)d_in[13], *p3 = (const float*)d_in[14];
  const float* l1w = (const float*)d_in[15], *l1b = (const float*)d_in[16];
  const float* l2w = (const float*)d_in[17], *l2b = (const float*)d_in[18];
  const float* l3w = (const float*)d_in[19], *l3b = (const float*)d_in[20];
  float* out = (float*)d_out;

  gnn_topk_kernel<<<dim3(NGRAPH), dim3(1024), 0, stream>>>(
      x_ids, eidx, emb,
      w1, b1, u1, p1, w2, b2, u2, p2, w3, b3, u3, p3,
      l1w, l1b, l2w, l2b, l3w, l3b, out);
}

// Round 11
// 269.574 us; speedup vs baseline: 2.3206x; 1.3601x over previous
//
#include <hip/hip_runtime.h>

#define NGRAPH 256
#define NNODE  1000
#define NEDGE  16000
#define DIM    32
#define HSTR   20   // h row stride in floats (80B: 16B-aligned)

__device__ __forceinline__ unsigned monof(float f) {
  unsigned b = __float_as_uint(f);
  return (b & 0x80000000u) ? ~b : (b | 0x80000000u);
}

__device__ __forceinline__ float4 f4max(float4 a, float4 b) {
  return make_float4(fmaxf(a.x,b.x), fmaxf(a.y,b.y), fmaxf(a.z,b.z), fmaxf(a.w,b.w));
}
__device__ __forceinline__ float4 f4relu(float4 a) {
  return make_float4(fmaxf(a.x,0.f), fmaxf(a.y,0.f), fmaxf(a.z,0.f), fmaxf(a.w,0.f));
}
__device__ __forceinline__ float4 f4scale(float4 a, float s) {
  return make_float4(a.x*s, a.y*s, a.z*s, a.w*s);
}
__device__ __forceinline__ float4 f4add(float4 a, float4 b) {
  return make_float4(a.x+b.x, a.y+b.y, a.z+b.z, a.w+b.w);
}
__device__ __forceinline__ float dot4(float4 a, float4 b) {
  return a.x*b.x + a.y*b.y + a.z*b.z + a.w*b.w;
}
__device__ __forceinline__ float4 shfl4(float4 v, int m) {
  return make_float4(__shfl_xor(v.x,m,64), __shfl_xor(v.y,m,64),
                     __shfl_xor(v.z,m,64), __shfl_xor(v.w,m,64));
}
__device__ __forceinline__ float4 lds4(const float* p) { return *(const float4*)p; }

struct __align__(16) Smem {
  union { float h[NNODE * HSTR]; unsigned stage[NEDGE]; } hu;  // 80000 B
  unsigned short csr[NEDGE];      // 32000 (layer-1 dst-buckets, PERSISTS)
  unsigned rowStart[1004];        // 4016  (layer-1 bucket offsets, PERSISTS)
  unsigned cnt[1024];             // 4096  (layer-1 build only)
  float score[1024];              // 4096
  unsigned short perm[1024];      // 2048
  short nidx[1024];               // 2048
  short mp[1024];                 // 2048  orig -> current id
  unsigned short orig_of[1024];   // 2048  current -> orig id
  unsigned histA[257];            // 1028
  unsigned histB[257];            // 1028
  unsigned wsum[16];              // 64
  float redm[512];                // 2048
  float reds[512];                // 2048
  float eacc[64];                 // 256
  float hbuf[48];                 // 192  => ~139 KB total (<160 KiB)
};

// exclusive block scan over 1024 threads; leaves total in wsum[15]
__device__ __forceinline__ unsigned blockExclScan(unsigned v, unsigned* wsum, int tid) {
  __syncthreads();
  int lane = tid & 63, w = tid >> 6;
  unsigned x = v;
  #pragma unroll
  for (int d = 1; d < 64; d <<= 1) {
    unsigned t = __shfl_up(x, d, 64);
    if (lane >= d) x += t;
  }
  if (lane == 63) wsum[w] = x;
  __syncthreads();
  if (w == 0) {
    unsigned s = (lane < 16) ? wsum[lane] : 0u;
    #pragma unroll
    for (int d = 1; d < 16; d <<= 1) {
      unsigned t = __shfl_up(s, d, 64);
      if (lane >= d) s += t;
    }
    if (lane < 16) wsum[lane] = s;
  }
  __syncthreads();
  unsigned base = (w > 0) ? wsum[w - 1] : 0u;
  return base + x - v;
}

// dot of 8 float4 weight words against x0..x7 (locals in scope)
#define XDOT(P4, R, S, O) ( dot4((P4)[(R)*(S)+(O)  ], x0) + dot4((P4)[(R)*(S)+(O)+1], x1) \
                          + dot4((P4)[(R)*(S)+(O)+2], x2) + dot4((P4)[(R)*(S)+(O)+3], x3) \
                          + dot4((P4)[(R)*(S)+(O)+4], x4) + dot4((P4)[(R)*(S)+(O)+5], x5) \
                          + dot4((P4)[(R)*(S)+(O)+6], x6) + dot4((P4)[(R)*(S)+(O)+7], x7) )
// dot of 4 float4 U words against h0..h3 (aggregated half)
#define GDOT(R, O) ( dot4(U4[(R)*16+(O)  ], h0) + dot4(U4[(R)*16+(O)+1], h1) \
                   + dot4(U4[(R)*16+(O)+2], h2) + dot4(U4[(R)*16+(O)+3], h3) )
#define ACC4(v, R)    v.x  = XDOT(U4,(R),16,8); v.y  = XDOT(U4,(R)+1,16,8); v.z  = XDOT(U4,(R)+2,16,8); v.w  = XDOT(U4,(R)+3,16,8);
#define ACC4ADD(v, R, O) v.x += GDOT((R),(O)); v.y += GDOT((R)+1,(O)); v.z += GDOT((R)+2,(O)); v.w += GDOT((R)+3,(O));
#define HV4(v, R)     v.x = fmaxf(Bv[(R)]+XDOT(W4,(R),8,0),0.f); v.y = fmaxf(Bv[(R)+1]+XDOT(W4,(R)+1,8,0),0.f); \
                      v.z = fmaxf(Bv[(R)+2]+XDOT(W4,(R)+2,8,0),0.f); v.w = fmaxf(Bv[(R)+3]+XDOT(W4,(R)+3,8,0),0.f);
#define REDCH(v, OFF) do { \
  float4 mx = act ? (v) : make_float4(-__builtin_inff(),-__builtin_inff(),-__builtin_inff(),-__builtin_inff()); \
  float4 sv = act ? (v) : make_float4(0.f,0.f,0.f,0.f); \
  mx = f4max(mx, shfl4(mx,32)); sv = f4add(sv, shfl4(sv,32)); \
  mx = f4max(mx, shfl4(mx,16)); sv = f4add(sv, shfl4(sv,16)); \
  mx = f4max(mx, shfl4(mx, 8)); sv = f4add(sv, shfl4(sv, 8)); \
  mx = f4max(mx, shfl4(mx, 4)); sv = f4add(sv, shfl4(sv, 4)); \
  mx = f4max(mx, shfl4(mx, 2)); sv = f4add(sv, shfl4(sv, 2)); \
  mx = f4max(mx, shfl4(mx, 1)); sv = f4add(sv, shfl4(sv, 1)); \
  if (lane == 0) { *((float4*)(sm.redm + wv*32 + (OFF))) = mx; *((float4*)(sm.reds + wv*32 + (OFF))) = sv; } \
} while (0)

extern "C" __global__ void
__attribute__((amdgpu_flat_work_group_size(1024,1024)))
__attribute__((amdgpu_waves_per_eu(4,4)))
gnn_topk_kernel(const int* __restrict__ x_ids, const int* __restrict__ eidx,
                const float* __restrict__ emb,
                const float* __restrict__ w1, const float* __restrict__ b1,
                const float* __restrict__ u1, const float* __restrict__ p1,
                const float* __restrict__ w2, const float* __restrict__ b2,
                const float* __restrict__ u2, const float* __restrict__ p2,
                const float* __restrict__ w3, const float* __restrict__ b3,
                const float* __restrict__ u3, const float* __restrict__ p3,
                const float* __restrict__ l1w, const float* __restrict__ l1b,
                const float* __restrict__ l2w, const float* __restrict__ l2b,
                const float* __restrict__ l3w, const float* __restrict__ l3b,
                float* __restrict__ out)
{
  const int g = blockIdx.x;
  const int tid = (int)threadIdx.x;
  const int lane = tid & 63, wv = tid >> 6;

  __shared__ Smem sm;
  float* h_lds = sm.hu.h;

  const int* esrc = eidx + (size_t)g * (2 * NEDGE);
  const int* edst = esrc + NEDGE;

  // ---- init: x = emb[ids] ----
  float4 x0,x1,x2,x3,x4,x5,x6,x7;
  if (tid < NNODE) {
    int id = x_ids[(size_t)g * NNODE + tid];
    const float4* ep = (const float4*)(emb + id * DIM);
    x0=ep[0]; x1=ep[1]; x2=ep[2]; x3=ep[3]; x4=ep[4]; x5=ep[5]; x6=ep[6]; x7=ep[7];
  } else {
    x0=x1=x2=x3=x4=x5=x6=x7=make_float4(0.f,0.f,0.f,0.f);
  }
  sm.mp[tid] = (tid < NNODE) ? (short)tid : (short)-1;
  sm.orig_of[tid] = (unsigned short)tid;
  if (tid < 64) sm.eacc[tid] = 0.f;
  __syncthreads();

  int n = NNODE;
  #pragma unroll 1
  for (int layer = 0; layer < 3; ++layer) {
    const float* W  = (layer==0)? w1 : (layer==1)? w2 : w3;
    const float* Bv = (layer==0)? b1 : (layer==1)? b2 : b3;
    const float* U  = (layer==0)? u1 : (layer==1)? u2 : u3;
    const float* P  = (layer==0)? p1 : (layer==1)? p2 : p3;
    const int k     = (layer==0)? 800 : (layer==1)? 640 : 512;
    const float4* W4 = (const float4*)W;
    const float4* U4 = (const float4*)U;

    // ---- CSR build: ONCE (layer 0). Buckets stay valid for layers 1,2 because
    //      topk renumbering is monotone -> bucket-of-orig-dst == bucket-of-cur-dst.
    if (layer == 0) {
      sm.cnt[tid] = 0u;
      __syncthreads();
      for (int e = tid; e < NEDGE; e += 1024) {
        int s = esrc[e];
        int d = edst[e];
        atomicAdd(&sm.cnt[d], 1u);
        sm.hu.stage[e] = ((unsigned)d << 16) | (unsigned)s;
      }
      __syncthreads();
      unsigned cv = sm.cnt[tid];
      unsigned excl = blockExclScan(cv, sm.wsum, tid);
      unsigned total = sm.wsum[15];
      if (tid < NNODE) sm.rowStart[tid] = excl;
      if (tid == 0) sm.rowStart[NNODE] = total;
      sm.cnt[tid] = excl;              // cursor
      __syncthreads();
      for (int e = tid; e < NEDGE; e += 1024) {
        unsigned pk = sm.hu.stage[e];
        unsigned d = pk >> 16;
        unsigned pos = atomicAdd(&sm.cnt[d], 1u);
        sm.csr[pos] = (unsigned short)(pk & 0xFFFFu);
      }
      __syncthreads();   // stage consumed; csr complete; h region reusable
    }

    // per-thread bucket (layer-1 bucket of this node's ORIGINAL id)
    unsigned wbeg = 0, wend = 0;
    if (tid < n) {
      int o = sm.orig_of[tid];
      wbeg = sm.rowStart[o];
      wend = sm.rowStart[o + 1];
    }

    float4* hp = (float4*)(h_lds + tid * HSTR);

    // ---- SAGE: acc = U[:,32:64]@x ; h0..h3 = relu(W[0:16]@x+b) ----
    float4 a0,a1,a2,a3,a4,a5,a6,a7;
    float4 h0,h1,h2,h3;
    if (tid < n) {
      ACC4(a0,0) ACC4(a1,4) ACC4(a2,8) ACC4(a3,12) ACC4(a4,16) ACC4(a5,20) ACC4(a6,24) ACC4(a7,28)
      HV4(h0,0) HV4(h1,4) HV4(h2,8) HV4(h3,12)
      hp[0]=h0; hp[1]=h1; hp[2]=h2; hp[3]=h3;
    }
    __syncthreads();   // h half0 visible
    if (tid < n) {
      for (unsigned e = wbeg; e < wend; ++e) {
        int s = sm.mp[sm.csr[e]];
        if (s >= 0) {
          const float* rp = h_lds + s * HSTR;
          h0 = f4max(h0, lds4(rp));   h1 = f4max(h1, lds4(rp+4));
          h2 = f4max(h2, lds4(rp+8)); h3 = f4max(h3, lds4(rp+12));
        }
      }
      ACC4ADD(a0,0,0) ACC4ADD(a1,4,0) ACC4ADD(a2,8,0) ACC4ADD(a3,12,0)
      ACC4ADD(a4,16,0) ACC4ADD(a5,20,0) ACC4ADD(a6,24,0) ACC4ADD(a7,28,0)
    }
    __syncthreads();
    if (tid < n) {
      HV4(h0,16) HV4(h1,20) HV4(h2,24) HV4(h3,28)
      hp[0]=h0; hp[1]=h1; hp[2]=h2; hp[3]=h3;
    }
    __syncthreads();
    if (tid < n) {
      for (unsigned e = wbeg; e < wend; ++e) {
        int s = sm.mp[sm.csr[e]];
        if (s >= 0) {
          const float* rp = h_lds + s * HSTR;
          h0 = f4max(h0, lds4(rp));   h1 = f4max(h1, lds4(rp+4));
          h2 = f4max(h2, lds4(rp+8)); h3 = f4max(h3, lds4(rp+12));
        }
      }
      ACC4ADD(a0,0,4) ACC4ADD(a1,4,4) ACC4ADD(a2,8,4) ACC4ADD(a3,12,4)
      ACC4ADD(a4,16,4) ACC4ADD(a5,20,4) ACC4ADD(a6,24,4) ACC4ADD(a7,28,4)
      x0=f4relu(a0); x1=f4relu(a1); x2=f4relu(a2); x3=f4relu(a3);
      x4=f4relu(a4); x5=f4relu(a5); x6=f4relu(a6); x7=f4relu(a7);
    }

    // ---- pool: score = tanh(x.p/||p||) ----
    float pn = 0.f;
    for (int c = 0; c < DIM; ++c) pn += P[c] * P[c];
    pn = sqrtf(pn);
    const float4* P4 = (const float4*)P;
    unsigned key = 0xFFFFFFFFu;
    if (tid < n) {
      float dp = dot4(P4[0],x0)+dot4(P4[1],x1)+dot4(P4[2],x2)+dot4(P4[3],x3)
               + dot4(P4[4],x4)+dot4(P4[5],x5)+dot4(P4[6],x6)+dot4(P4[7],x7);
      float sc = tanhf(dp / pn);
      sm.score[tid] = sc;
      key = ~monof(sc);
    }
    __syncthreads();   // last h-row reads done -> rows free
    // stash x half0 in rows; zero both histograms (disjoint writes, same phase)
    if (tid < n) { hp[0]=x0; hp[1]=x1; hp[2]=x2; hp[3]=x3; }
    for (int i = tid; i < 257; i += 1024) { sm.histA[i] = 0u; sm.histB[i] = 0u; }
    __syncthreads();

    // ---- exact top-k: 4-pass radix select, ping-pong histograms ----
    bool cand = (tid < n);
    bool sel = false;
    unsigned target = (unsigned)k;
    unsigned dig = (key >> 24) & 255u;
    if (cand) atomicAdd(&sm.histA[dig], 1u);
    __syncthreads();
    #pragma unroll 1
    for (int p = 0; p < 4; ++p) {
      unsigned* buf  = (p & 1) ? sm.histB : sm.histA;
      unsigned* nbuf = (p & 1) ? sm.histA : sm.histB;
      if (tid < 64) {   // wave0: exclusive scan of 256 bins of buf
        unsigned q0 = buf[tid*4], q1 = buf[tid*4+1], q2 = buf[tid*4+2], q3 = buf[tid*4+3];
        unsigned s1 = q0+q1, s2v = s1+q2, s3 = s2v+q3;
        unsigned tot = s3;
        #pragma unroll
        for (int d = 1; d < 64; d <<= 1) {
          unsigned t = __shfl_up(tot, d, 64);
          if (lane >= d) tot += t;
        }
        unsigned base = tot - s3;
        buf[tid*4] = base; buf[tid*4+1] = base+q0; buf[tid*4+2] = base+s1; buf[tid*4+3] = base+s2v;
        if (tid == 63) buf[256] = tot;
      } else if (p > 0 && p < 3) {   // re-zero the other buffer for pass p+1
        for (int i = tid - 64; i < 257; i += 960) nbuf[i] = 0u;
      }
      __syncthreads();
      if (cand) {
        unsigned lo = buf[dig], hi = buf[dig+1];
        if (hi <= target)      { sel = true;  cand = false; }
        else if (lo >= target) { cand = false; }
        else                   { target -= lo; }
      }
      if (p < 3) {
        dig = (key >> (16 - 8*p)) & 255u;
        if (cand) atomicAdd(&nbuf[dig], 1u);
      }
      __syncthreads();
    }
    // merged tie-resolution + position scan: packed (cand<<16)|sel
    unsigned packed = (cand ? 0x10000u : 0u) | (sel ? 1u : 0u);
    unsigned r = blockExclScan(packed, sm.wsum, tid);
    unsigned trank = r >> 16, sScan = r & 0xFFFFu;
    if (cand && trank < target) sel = true;
    unsigned pos = sScan + ((trank < target) ? trank : target);
    sm.nidx[tid] = -1;
    __syncthreads();
    if (sel) { sm.nidx[tid] = (short)pos; sm.perm[pos] = (unsigned short)tid; }
    __syncthreads();

    // ---- gather xn = x[perm]*vals (half0 already in rows) ----
    float4 n0,n1,n2,n3; float val = 0.f; int pj = 0; int onew = 0;
    if (tid < k) {
      pj = sm.perm[tid];
      val = sm.score[pj];
      onew = sm.orig_of[pj];
      const float* rp = h_lds + pj * HSTR;
      n0 = f4scale(lds4(rp),   val); n1 = f4scale(lds4(rp+4),  val);
      n2 = f4scale(lds4(rp+8), val); n3 = f4scale(lds4(rp+12), val);
    }
    __syncthreads();
    if (tid < n) { hp[0]=x4; hp[1]=x5; hp[2]=x6; hp[3]=x7; }
    __syncthreads();
    if (tid < k) {
      const float* rp = h_lds + pj * HSTR;
      x4 = f4scale(lds4(rp),   val); x5 = f4scale(lds4(rp+4),  val);
      x6 = f4scale(lds4(rp+8), val); x7 = f4scale(lds4(rp+12), val);
      x0 = n0; x1 = n1; x2 = n2; x3 = n3;
      sm.orig_of[tid] = (unsigned short)onew;   // reads were 2 barriers ago
    } else {
      x0=x1=x2=x3=x4=x5=x6=x7=make_float4(0.f,0.f,0.f,0.f);
    }
    // compose orig->current map
    {
      short m0 = sm.mp[tid];
      if (m0 >= 0) sm.mp[tid] = sm.nidx[m0];
    }
    n = k;

    // ---- readout: gmp || gap on pooled x, accumulate into eacc ----
    {
      bool act = (tid < n);
      REDCH(x0, 0); REDCH(x1, 4); REDCH(x2, 8);  REDCH(x3, 12);
      REDCH(x4,16); REDCH(x5,20); REDCH(x6,24);  REDCH(x7,28);
    }
    __syncthreads();
    if (tid < 32) {
      float rm = -__builtin_inff(), rs = 0.f;
      #pragma unroll
      for (int w_ = 0; w_ < 16; ++w_) {
        rm = fmaxf(rm, sm.redm[w_*32 + tid]);
        rs += sm.reds[w_*32 + tid];
      }
      sm.eacc[tid] += rm;
      sm.eacc[32 + tid] += rs / (float)n;
    }
    __syncthreads();
  }

  // ---- MLP head ----
  if (tid < 32) {
    float v = l1b[tid];
    #pragma unroll
    for (int c = 0; c < 64; ++c) v += l1w[tid*64 + c] * sm.eacc[c];
    sm.hbuf[tid] = fmaxf(v, 0.f);
  }
  __syncthreads();
  if (tid < 16) {
    float v = l2b[tid];
    #pragma unroll
    for (int c = 0; c < 32; ++c) v += l2w[tid*32 + c] * sm.hbuf[c];
    sm.hbuf[32 + tid] = fmaxf(v, 0.f);
  }
  __syncthreads();
  if (tid == 0) {
    float v = l3b[0];
    #pragma unroll
    for (int c = 0; c < 16; ++c) v += l3w[c] * sm.hbuf[32 + c];
    out[g] = 1.f / (1.f + expf(-v));
  }
  if (tid < 64) out[NGRAPH + (size_t)g*64 + tid] = sm.eacc[tid];
}

extern "C" void kernel_launch(void* const* d_in, const int* in_sizes, int n_in,
                              void* d_out, int out_size, void* d_ws, size_t ws_size,
                              hipStream_t stream) {
  (void)in_sizes; (void)n_in; (void)d_ws; (void)ws_size; (void)out_size;
  const int*   x_ids = (const int*)d_in[0];
  const int*   eidx  = (const int*)d_in[1];
  const float* emb   = (const float*)d_in[2];
  const float* w1 = (const float*)d_in[3],  *b1 = (const float*)d_in[4];
  const float* u1 = (const float*)d_in[5],  *p1 = (const float*)d_in[6];
  const float* w2 = (const float*)d_in[7],  *b2 = (const float*)d_in[8];
  const float* u2 = (const float*)d_in[9],  *p2 = (const float*)d_in[10];
  const float* w3 = (const float*)d_in[11], *b3 = (const float*)d_in[12];
  const float* u3 = (const float*)d_in[13], *p3 = (const float*)d_in[14];
  const float* l1w = (const float*)d_in[15], *l1b = (const float*)d_in[16];
  const float* l2w = (const float*)d_in[17], *l2b = (const float*)d_in[18];
  const float* l3w = (const float*)d_in[19], *l3b = (const float*)d_in[20];
  float* out = (float*)d_out;

  gnn_topk_kernel<<<dim3(NGRAPH), dim3(1024), 0, stream>>>(
      x_ids, eidx, emb,
      w1, b1, u1, p1, w2, b2, u2, p2, w3, b3, u3, p3,
      l1w, l1b, l2w, l2b, l3w, l3b, out);
}

// Round 12
// 260.080 us; speedup vs baseline: 2.4053x; 1.0365x over previous
//
#include <hip/hip_runtime.h>

#define NGRAPH 256
#define NNODE  1000
#define NEDGE  16000
#define DIM    32
#define HSTR   20   // h row stride in floats (80B: 16B-aligned)

__device__ __forceinline__ unsigned monof(float f) {
  unsigned b = __float_as_uint(f);
  return (b & 0x80000000u) ? ~b : (b | 0x80000000u);
}

__device__ __forceinline__ float4 f4max(float4 a, float4 b) {
  return make_float4(fmaxf(a.x,b.x), fmaxf(a.y,b.y), fmaxf(a.z,b.z), fmaxf(a.w,b.w));
}
__device__ __forceinline__ float4 f4relu(float4 a) {
  return make_float4(fmaxf(a.x,0.f), fmaxf(a.y,0.f), fmaxf(a.z,0.f), fmaxf(a.w,0.f));
}
__device__ __forceinline__ float4 f4scale(float4 a, float s) {
  return make_float4(a.x*s, a.y*s, a.z*s, a.w*s);
}
__device__ __forceinline__ float4 f4add(float4 a, float4 b) {
  return make_float4(a.x+b.x, a.y+b.y, a.z+b.z, a.w+b.w);
}
__device__ __forceinline__ float dot4(float4 a, float4 b) {
  return a.x*b.x + a.y*b.y + a.z*b.z + a.w*b.w;
}
__device__ __forceinline__ float4 shfl4(float4 v, int m) {
  return make_float4(__shfl_xor(v.x,m,64), __shfl_xor(v.y,m,64),
                     __shfl_xor(v.z,m,64), __shfl_xor(v.w,m,64));
}
__device__ __forceinline__ float4 lds4(const float* p) { return *(const float4*)p; }

struct __align__(16) Smem {
  union { float h[NNODE * HSTR]; unsigned stage[NEDGE]; } hu;  // 80000 B
  unsigned short csr[NEDGE];      // 32000 (orig-dst buckets, built once)
  unsigned rowStart[1004];        // 4016
  unsigned cnt[1024];             // 4096 (build only)
  unsigned histA[257];            // 1028
  unsigned histB[257];            // 1028
  unsigned wsum[16];              // 64
  float redm[512];                // 2048
  float reds[512];                // 2048
  float eacc[64];                 // 256
  float hbuf[48];                 // 192
  unsigned char alv[1024];        // 1024  alive mask, orig-id indexed
};                                 // ~128 KB total

// exclusive block scan over 1024 threads; leaves total in wsum[15]
__device__ __forceinline__ unsigned blockExclScan(unsigned v, unsigned* wsum, int tid) {
  __syncthreads();
  int lane = tid & 63, w = tid >> 6;
  unsigned x = v;
  #pragma unroll
  for (int d = 1; d < 64; d <<= 1) {
    unsigned t = __shfl_up(x, d, 64);
    if (lane >= d) x += t;
  }
  if (lane == 63) wsum[w] = x;
  __syncthreads();
  if (w == 0) {
    unsigned s = (lane < 16) ? wsum[lane] : 0u;
    #pragma unroll
    for (int d = 1; d < 16; d <<= 1) {
      unsigned t = __shfl_up(s, d, 64);
      if (lane >= d) s += t;
    }
    if (lane < 16) wsum[lane] = s;
  }
  __syncthreads();
  unsigned base = (w > 0) ? wsum[w - 1] : 0u;
  return base + x - v;
}

// dot of 8 float4 weight words against x0..x7 (locals in scope)
#define XDOT(P4, R, S, O) ( dot4((P4)[(R)*(S)+(O)  ], x0) + dot4((P4)[(R)*(S)+(O)+1], x1) \
                          + dot4((P4)[(R)*(S)+(O)+2], x2) + dot4((P4)[(R)*(S)+(O)+3], x3) \
                          + dot4((P4)[(R)*(S)+(O)+4], x4) + dot4((P4)[(R)*(S)+(O)+5], x5) \
                          + dot4((P4)[(R)*(S)+(O)+6], x6) + dot4((P4)[(R)*(S)+(O)+7], x7) )
// dot of 4 float4 U words against h0..h3 (aggregated half)
#define GDOT(R, O) ( dot4(U4[(R)*16+(O)  ], h0) + dot4(U4[(R)*16+(O)+1], h1) \
                   + dot4(U4[(R)*16+(O)+2], h2) + dot4(U4[(R)*16+(O)+3], h3) )
#define ACC4(v, R)    v.x  = XDOT(U4,(R),16,8); v.y  = XDOT(U4,(R)+1,16,8); v.z  = XDOT(U4,(R)+2,16,8); v.w  = XDOT(U4,(R)+3,16,8);
#define ACC4ADD(v, R, O) v.x += GDOT((R),(O)); v.y += GDOT((R)+1,(O)); v.z += GDOT((R)+2,(O)); v.w += GDOT((R)+3,(O));
#define HV4(v, R)     v.x = fmaxf(Bv[(R)]+XDOT(W4,(R),8,0),0.f); v.y = fmaxf(Bv[(R)+1]+XDOT(W4,(R)+1,8,0),0.f); \
                      v.z = fmaxf(Bv[(R)+2]+XDOT(W4,(R)+2,8,0),0.f); v.w = fmaxf(Bv[(R)+3]+XDOT(W4,(R)+3,8,0),0.f);
#define REDCH(v, OFF) do { \
  float4 mx = act ? (v) : make_float4(-__builtin_inff(),-__builtin_inff(),-__builtin_inff(),-__builtin_inff()); \
  float4 sv = act ? (v) : make_float4(0.f,0.f,0.f,0.f); \
  mx = f4max(mx, shfl4(mx,32)); sv = f4add(sv, shfl4(sv,32)); \
  mx = f4max(mx, shfl4(mx,16)); sv = f4add(sv, shfl4(sv,16)); \
  mx = f4max(mx, shfl4(mx, 8)); sv = f4add(sv, shfl4(sv, 8)); \
  mx = f4max(mx, shfl4(mx, 4)); sv = f4add(sv, shfl4(sv, 4)); \
  mx = f4max(mx, shfl4(mx, 2)); sv = f4add(sv, shfl4(sv, 2)); \
  mx = f4max(mx, shfl4(mx, 1)); sv = f4add(sv, shfl4(sv, 1)); \
  if (lane == 0) { *((float4*)(sm.redm + wv*32 + (OFF))) = mx; *((float4*)(sm.reds + wv*32 + (OFF))) = sv; } \
} while (0)

extern "C" __global__ void
__attribute__((amdgpu_flat_work_group_size(1024,1024)))
__attribute__((amdgpu_waves_per_eu(4,4)))
gnn_topk_kernel(const int* __restrict__ x_ids, const int* __restrict__ eidx,
                const float* __restrict__ emb,
                const float* __restrict__ w1, const float* __restrict__ b1,
                const float* __restrict__ u1, const float* __restrict__ p1,
                const float* __restrict__ w2, const float* __restrict__ b2,
                const float* __restrict__ u2, const float* __restrict__ p2,
                const float* __restrict__ w3, const float* __restrict__ b3,
                const float* __restrict__ u3, const float* __restrict__ p3,
                const float* __restrict__ l1w, const float* __restrict__ l1b,
                const float* __restrict__ l2w, const float* __restrict__ l2b,
                const float* __restrict__ l3w, const float* __restrict__ l3b,
                float* __restrict__ out)
{
  const int g = blockIdx.x;
  const int tid = (int)threadIdx.x;
  const int lane = tid & 63, wv = tid >> 6;

  __shared__ Smem sm;
  float* h_lds = sm.hu.h;

  const int* esrc = eidx + (size_t)g * (2 * NEDGE);
  const int* edst = esrc + NEDGE;

  // ---- init: x = emb[ids]; every node stays in its original thread forever ----
  float4 x0,x1,x2,x3,x4,x5,x6,x7;
  bool alive = (tid < NNODE);
  if (alive) {
    int id = x_ids[(size_t)g * NNODE + tid];
    const float4* ep = (const float4*)(emb + id * DIM);
    x0=ep[0]; x1=ep[1]; x2=ep[2]; x3=ep[3]; x4=ep[4]; x5=ep[5]; x6=ep[6]; x7=ep[7];
  } else {
    x0=x1=x2=x3=x4=x5=x6=x7=make_float4(0.f,0.f,0.f,0.f);
  }
  sm.alv[tid] = alive ? 1 : 0;
  if (tid < 64) sm.eacc[tid] = 0.f;
  __syncthreads();

  #pragma unroll 1
  for (int layer = 0; layer < 3; ++layer) {
    const float* W  = (layer==0)? w1 : (layer==1)? w2 : w3;
    const float* Bv = (layer==0)? b1 : (layer==1)? b2 : b3;
    const float* U  = (layer==0)? u1 : (layer==1)? u2 : u3;
    const float* P  = (layer==0)? p1 : (layer==1)? p2 : p3;
    const int k     = (layer==0)? 800 : (layer==1)? 640 : 512;
    const float4* W4 = (const float4*)W;
    const float4* U4 = (const float4*)U;

    // ---- CSR build: ONCE (layer 0); buckets indexed by original dst id ----
    if (layer == 0) {
      sm.cnt[tid] = 0u;
      __syncthreads();
      for (int e = tid; e < NEDGE; e += 1024) {
        int s = esrc[e];
        int d = edst[e];
        atomicAdd(&sm.cnt[d], 1u);
        sm.hu.stage[e] = ((unsigned)d << 16) | (unsigned)s;
      }
      __syncthreads();
      unsigned cv = sm.cnt[tid];
      unsigned excl = blockExclScan(cv, sm.wsum, tid);
      unsigned total = sm.wsum[15];
      if (tid < NNODE) sm.rowStart[tid] = excl;
      if (tid == 0) sm.rowStart[NNODE] = total;
      sm.cnt[tid] = excl;              // cursor
      __syncthreads();
      for (int e = tid; e < NEDGE; e += 1024) {
        unsigned pk = sm.hu.stage[e];
        unsigned d = pk >> 16;
        unsigned pos = atomicAdd(&sm.cnt[d], 1u);
        sm.csr[pos] = (unsigned short)(pk & 0xFFFFu);
      }
      __syncthreads();   // stage consumed; csr complete; h region reusable
    }

    unsigned wbeg = 0, wend = 0;
    if (tid < NNODE) { wbeg = sm.rowStart[tid]; wend = sm.rowStart[tid + 1]; }

    float4* hp = (float4*)(h_lds + tid * HSTR);

    // ---- SAGE: acc = U[:,32:64]@x ; h0..h3 = relu(W[0:16]@x+b) ----
    float4 a0,a1,a2,a3,a4,a5,a6,a7;
    float4 h0,h1,h2,h3;
    if (alive) {
      ACC4(a0,0) ACC4(a1,4) ACC4(a2,8) ACC4(a3,12) ACC4(a4,16) ACC4(a5,20) ACC4(a6,24) ACC4(a7,28)
      HV4(h0,0) HV4(h1,4) HV4(h2,8) HV4(h3,12)
      hp[0]=h0; hp[1]=h1; hp[2]=h2; hp[3]=h3;
    }
    __syncthreads();   // h half0 visible
    if (alive) {
      for (unsigned e = wbeg; e < wend; ++e) {
        int s = sm.csr[e];
        if (sm.alv[s]) {
          const float* rp = h_lds + s * HSTR;
          h0 = f4max(h0, lds4(rp));   h1 = f4max(h1, lds4(rp+4));
          h2 = f4max(h2, lds4(rp+8)); h3 = f4max(h3, lds4(rp+12));
        }
      }
      ACC4ADD(a0,0,0) ACC4ADD(a1,4,0) ACC4ADD(a2,8,0) ACC4ADD(a3,12,0)
      ACC4ADD(a4,16,0) ACC4ADD(a5,20,0) ACC4ADD(a6,24,0) ACC4ADD(a7,28,0)
    }
    __syncthreads();
    if (alive) {
      HV4(h0,16) HV4(h1,20) HV4(h2,24) HV4(h3,28)
      hp[0]=h0; hp[1]=h1; hp[2]=h2; hp[3]=h3;
    }
    __syncthreads();
    if (alive) {
      for (unsigned e = wbeg; e < wend; ++e) {
        int s = sm.csr[e];
        if (sm.alv[s]) {
          const float* rp = h_lds + s * HSTR;
          h0 = f4max(h0, lds4(rp));   h1 = f4max(h1, lds4(rp+4));
          h2 = f4max(h2, lds4(rp+8)); h3 = f4max(h3, lds4(rp+12));
        }
      }
      ACC4ADD(a0,0,4) ACC4ADD(a1,4,4) ACC4ADD(a2,8,4) ACC4ADD(a3,12,4)
      ACC4ADD(a4,16,4) ACC4ADD(a5,20,4) ACC4ADD(a6,24,4) ACC4ADD(a7,28,4)
      x0=f4relu(a0); x1=f4relu(a1); x2=f4relu(a2); x3=f4relu(a3);
      x4=f4relu(a4); x5=f4relu(a5); x6=f4relu(a6); x7=f4relu(a7);
    }

    // ---- pool: score = tanh(x.p/||p||) (own score stays in a register) ----
    float pn = 0.f;
    for (int c = 0; c < DIM; ++c) pn += P[c] * P[c];
    pn = sqrtf(pn);
    const float4* P4 = (const float4*)P;
    unsigned key = 0xFFFFFFFFu;
    float val = 0.f;
    if (alive) {
      float dp = dot4(P4[0],x0)+dot4(P4[1],x1)+dot4(P4[2],x2)+dot4(P4[3],x3)
               + dot4(P4[4],x4)+dot4(P4[5],x5)+dot4(P4[6],x6)+dot4(P4[7],x7);
      val = tanhf(dp / pn);
      key = ~monof(val);   // ascending key == descending score
    }
    for (int i = tid; i < 257; i += 1024) { sm.histA[i] = 0u; sm.histB[i] = 0u; }
    __syncthreads();

    // ---- exact top-k: 4-pass radix select, ping-pong histograms ----
    bool cand = alive;
    bool sel = false;
    unsigned target = (unsigned)k;
    unsigned dig = (key >> 24) & 255u;
    if (cand) atomicAdd(&sm.histA[dig], 1u);
    __syncthreads();
    #pragma unroll 1
    for (int p = 0; p < 4; ++p) {
      unsigned* buf  = (p & 1) ? sm.histB : sm.histA;
      unsigned* nbuf = (p & 1) ? sm.histA : sm.histB;
      if (tid < 64) {   // wave0: exclusive scan of 256 bins of buf
        unsigned q0 = buf[tid*4], q1 = buf[tid*4+1], q2 = buf[tid*4+2], q3 = buf[tid*4+3];
        unsigned s1 = q0+q1, s2v = s1+q2, s3 = s2v+q3;
        unsigned tot = s3;
        #pragma unroll
        for (int d = 1; d < 64; d <<= 1) {
          unsigned t = __shfl_up(tot, d, 64);
          if (lane >= d) tot += t;
        }
        unsigned base = tot - s3;
        buf[tid*4] = base; buf[tid*4+1] = base+q0; buf[tid*4+2] = base+s1; buf[tid*4+3] = base+s2v;
        if (tid == 63) buf[256] = tot;
      } else if (p > 0 && p < 3) {   // re-zero the other buffer for the next atomic
        for (int i = tid - 64; i < 257; i += 960) nbuf[i] = 0u;
      }
      __syncthreads();
      if (cand) {
        unsigned lo = buf[dig], hi = buf[dig+1];
        if (hi <= target)      { sel = true;  cand = false; }
        else if (lo >= target) { cand = false; }
        else                   { target -= lo; }
      }
      if (p < 3) {
        dig = (key >> (16 - 8*p)) & 255u;
        if (cand) atomicAdd(&nbuf[dig], 1u);
      }
      __syncthreads();
    }
    // tie resolution among pivot-equal candidates: smallest original tid wins
    // (== smallest current id, since renumbering was monotone)
    unsigned trank = blockExclScan(cand ? 1u : 0u, sm.wsum, tid);
    if (cand && trank < target) sel = true;

    // ---- select-in-place: no gather, no renumbering ----
    alive = sel;
    sm.alv[tid] = sel ? 1 : 0;   // visible to next layer's walks (syncs in between)
    if (sel) {
      x0=f4scale(x0,val); x1=f4scale(x1,val); x2=f4scale(x2,val); x3=f4scale(x3,val);
      x4=f4scale(x4,val); x5=f4scale(x5,val); x6=f4scale(x6,val); x7=f4scale(x7,val);
    } else {
      x0=x1=x2=x3=x4=x5=x6=x7=make_float4(0.f,0.f,0.f,0.f);
    }

    // ---- readout: gmp || gap over surviving nodes, accumulate into eacc ----
    {
      bool act = alive;
      REDCH(x0, 0); REDCH(x1, 4); REDCH(x2, 8);  REDCH(x3, 12);
      REDCH(x4,16); REDCH(x5,20); REDCH(x6,24);  REDCH(x7,28);
    }
    __syncthreads();
    if (tid < 32) {
      float rm = -__builtin_inff(), rs = 0.f;
      #pragma unroll
      for (int w_ = 0; w_ < 16; ++w_) {
        rm = fmaxf(rm, sm.redm[w_*32 + tid]);
        rs += sm.reds[w_*32 + tid];
      }
      sm.eacc[tid] += rm;
      sm.eacc[32 + tid] += rs / (float)k;
    }
    __syncthreads();
  }

  // ---- MLP head ----
  if (tid < 32) {
    float v = l1b[tid];
    #pragma unroll
    for (int c = 0; c < 64; ++c) v += l1w[tid*64 + c] * sm.eacc[c];
    sm.hbuf[tid] = fmaxf(v, 0.f);
  }
  __syncthreads();
  if (tid < 16) {
    float v = l2b[tid];
    #pragma unroll
    for (int c = 0; c < 32; ++c) v += l2w[tid*32 + c] * sm.hbuf[c];
    sm.hbuf[32 + tid] = fmaxf(v, 0.f);
  }
  __syncthreads();
  if (tid == 0) {
    float v = l3b[0];
    #pragma unroll
    for (int c = 0; c < 16; ++c) v += l3w[c] * sm.hbuf[32 + c];
    out[g] = 1.f / (1.f + expf(-v));
  }
  if (tid < 64) out[NGRAPH + (size_t)g*64 + tid] = sm.eacc[tid];
}

extern "C" void kernel_launch(void* const* d_in, const int* in_sizes, int n_in,
                              void* d_out, int out_size, void* d_ws, size_t ws_size,
                              hipStream_t stream) {
  (void)in_sizes; (void)n_in; (void)d_ws; (void)ws_size; (void)out_size;
  const int*   x_ids = (const int*)d_in[0];
  const int*   eidx  = (const int*)d_in[1];
  const float* emb   = (const float*)d_in[2];
  const float* w1 = (const float*)d_in[3],  *b1 = (const float*)d_in[4];
  const float* u1 = (const float*)d_in[5],  *p1 = (const float*)d_in[6];
  const float* w2 = (const float*)d_in[7],  *b2 = (const float*)d_in[8];
  const float* u2 = (const float*)d_in[9],  *p2 = (const float*)d_in[10];
  const float* w3 = (const float*)d_in[11], *b3 = (const float*)d_in[12];
  const float* u3 = (const float*)d_in[13], *p3 = (const float*)d_in[14];
  const float* l1w = (const float*)d_in[15], *l1b = (const float*)d_in[16];
  const float* l2w = (const float*)d_in[17], *l2b = (const float*)d_in[18];
  const float* l3w = (const float*)d_in[19], *l3b = (const float*)d_in[20];
  float* out = (float*)d_out;

  gnn_topk_kernel<<<dim3(NGRAPH), dim3(1024), 0, stream>>>(
      x_ids, eidx, emb,
      w1, b1, u1, p1, w2, b2, u2, p2, w3, b3, u3, p3,
      l1w, l1b, l2w, l2b, l3w, l3b, out);
}